// Round 16
// baseline (354.776 us; speedup 1.0000x reference)
//
#include <hip/hip_runtime.h>

typedef __attribute__((ext_vector_type(8))) short bf16x8;
typedef __attribute__((ext_vector_type(16))) float f32x16;

union FragU { bf16x8 v; unsigned int u[4]; };
struct Wptrs { const float* p[16]; };

#define ROWS 192
#define THREADS 512

__device__ __forceinline__ unsigned int bfb(float f) {
  unsigned int u = __builtin_bit_cast(unsigned int, f);
  return (u + 0x7fffu + ((u >> 16) & 1u)) >> 16;   // RNE f32 -> bf16 bits
}
__device__ __forceinline__ unsigned int cvtpk(float lo, float hi) {
  unsigned int d;
  asm("v_cvt_pk_bf16_f32 %0, %1, %2" : "=v"(d) : "v"(lo), "v"(hi));
  return d;
}
__device__ __forceinline__ float bf2f(unsigned short b) {
  return __builtin_bit_cast(float, (unsigned int)b << 16);
}
__device__ __forceinline__ f32x16 zero16() {
  f32x16 z;
  #pragma unroll
  for (int i = 0; i < 16; ++i) z[i] = 0.0f;
  return z;
}
__device__ __forceinline__ bf16x8 ldA(const unsigned short* __restrict__ wsb, int tile, int l31, int hi, int h) {
  return *(const bf16x8*)(wsb + ((tile * 32 + l31) << 5) + h * 16 + hi * 8);
}

// Weight-folded silu (W1 pre-scaled by c = -log2(e), W4 by -ln2; c*(-ln2)=1):
// acc arrives as a = c*z; next-layer input is h' = a * rcp(1 + exp2(a)).
// Pairwise shared reciprocal (R15-passed): r = rcp(d0*d1), h0 = a0*r*d1, ...
// C layout (32x32x16): col p = lane&31, row j = (reg&3)+8*(reg>>2)+4*hi.
// Next-layer B frags via 4x v_permlane32_swap_b32 (verified R1-R15 network).
__device__ __forceinline__ void transition(const f32x16& acc, bf16x8& b0, bf16x8& b1) {
  unsigned int P[8];
  #pragma unroll
  for (int t = 0; t < 8; ++t) {
    float a0 = acc[2*t], a1 = acc[2*t+1];
    float d0 = 1.0f + __builtin_amdgcn_exp2f(a0);
    float d1 = 1.0f + __builtin_amdgcn_exp2f(a1);
    float r  = __builtin_amdgcn_rcpf(d0 * d1);
    float h0 = a0 * r * d1;
    float h1 = a1 * r * d0;
    P[t] = cvtpk(h0, h1);
  }
  asm volatile("v_permlane32_swap_b32 %0, %1" : "+v"(P[0]), "+v"(P[2]));
  asm volatile("v_permlane32_swap_b32 %0, %1" : "+v"(P[1]), "+v"(P[3]));
  asm volatile("v_permlane32_swap_b32 %0, %1" : "+v"(P[4]), "+v"(P[6]));
  asm volatile("v_permlane32_swap_b32 %0, %1" : "+v"(P[5]), "+v"(P[7]));
  FragU f0, f1;
  f0.u[0] = P[0]; f0.u[1] = P[1]; f0.u[2] = P[2]; f0.u[3] = P[3];
  f1.u[0] = P[4]; f1.u[1] = P[5]; f1.u[2] = P[6]; f1.u[3] = P[7];
  b0 = f0.v; b1 = f1.v;
}

// T14 async-STAGE split. vb*8 <= 1536 = 3*THREADS -> fixed 3 quads/thread.
// load3: issue the global loads for a phase slice (pads/out-of-range = 0).
template<int NL, int OFF>
__device__ __forceinline__ void load3(const float* __restrict__ rad,
    int base, int vb, int tid, float4* L)
{
  #pragma unroll
  for (int k = 0; k < 3; ++k) {
    int j = tid + k * THREADS, i = j >> 3, q = j & 7;
    float4 g = make_float4(0.f, 0.f, 0.f, 0.f);
    if (q < NL / 4 && i < vb)
      g = *(const float4*)(rad + (long)(base + i) * 72 + OFF + q * 4);
    L[k] = g;
  }
}
// write3: pack + permuted LDS write (zeros land in the K-pads).
__device__ __forceinline__ void write3(unsigned short* __restrict__ s_in,
    const unsigned short* __restrict__ s_pos, int vb, int tid, const float4* L)
{
  #pragma unroll
  for (int k = 0; k < 3; ++k) {
    int j = tid + k * THREADS, i = j >> 3, q = j & 7;
    if (i < vb) {
      *(uint2*)(s_in + (int)s_pos[i] * 32 + q * 4) =
          make_uint2(cvtpk(L[k].x, L[k].y), cvtpk(L[k].z, L[k].w));
    }
  }
}

// Compute only (R13-verbatim body): species-uniform 32-row groups.
template<int NL, int OFF, int TB>
__device__ __forceinline__ void computePhase(const unsigned short* __restrict__ wsb,
    const unsigned short* __restrict__ s_in, unsigned short* __restrict__ s_out,
    const int* s_cnt, const int* s_off, const int* s_gpre, int tid)
{
  const int lane = tid & 63, wid = tid >> 6;
  const int l31 = lane & 31, hi = lane >> 5;
  const f32x16 Z = zero16();
  const int Gtot = s_gpre[4];
  for (int g = wid; g < Gtot; g += THREADS / 64) {
    int s = (g >= s_gpre[1]) + (g >= s_gpre[2]) + (g >= s_gpre[3]);
    int gi = g - s_gpre[s];
    int goff = s_off[s] + gi * 32;
    int gcnt = s_cnt[s] - gi * 32; if (gcnt > 32) gcnt = 32;
    int li = l31 < gcnt ? l31 : gcnt - 1;
    int row = goff + li;

    FragU bx0, bx1;
    bx0.v = *(const bf16x8*)(s_in + row * 32 + hi * 8);
    if (NL > 16) bx1.v = *(const bf16x8*)(s_in + row * 32 + 16 + hi * 8);

    f32x16 acc;
    acc = __builtin_amdgcn_mfma_f32_32x32x16_bf16(ldA(wsb, TB + s, l31, hi, 0), bx0.v, Z, 0, 0, 0);
    if (NL > 16)
      acc = __builtin_amdgcn_mfma_f32_32x32x16_bf16(ldA(wsb, TB + s, l31, hi, 1), bx1.v, acc, 0, 0, 0);
    bf16x8 b0, b1;
    transition(acc, b0, b1);
    acc = __builtin_amdgcn_mfma_f32_32x32x16_bf16(ldA(wsb, TB + 4 + s, l31, hi, 0), b0, Z, 0, 0, 0);
    acc = __builtin_amdgcn_mfma_f32_32x32x16_bf16(ldA(wsb, TB + 4 + s, l31, hi, 1), b1, acc, 0, 0, 0);
    transition(acc, b0, b1);
    acc = __builtin_amdgcn_mfma_f32_32x32x16_bf16(ldA(wsb, TB + 8 + s, l31, hi, 0), b0, Z, 0, 0, 0);
    acc = __builtin_amdgcn_mfma_f32_32x32x16_bf16(ldA(wsb, TB + 8 + s, l31, hi, 1), b1, acc, 0, 0, 0);
    transition(acc, b0, b1);
    acc = __builtin_amdgcn_mfma_f32_32x32x16_bf16(ldA(wsb, TB + 12 + s, l31, hi, 0), b0, Z, 0, 0, 0);
    acc = __builtin_amdgcn_mfma_f32_32x32x16_bf16(ldA(wsb, TB + 12 + s, l31, hi, 1), b1, acc, 0, 0, 0);

    // store: reg quad t -> jo = 8t + 4hi + 0..3 ; natural 72-stride s_out
    if (l31 < gcnt) {
      int obase = (goff + l31) * 72 + OFF;
      #pragma unroll
      for (int t = 0; t < 4; ++t) {
        if (8 * t + 4 * hi + 4 <= NL) {
          *(uint2*)(s_out + obase + 8 * t + 4 * hi) =
              make_uint2(cvtpk(acc[4*t], acc[4*t+1]), cvtpk(acc[4*t+2], acc[4*t+3]));
        }
      }
    }
  }
}

// weights -> bf16 fragment-ready layout in d_ws, with silu-constant folding:
// layer 0 (W1) scaled by -log2(e); layer 3 (W4) scaled by -ln2; W2/W3 as-is.
// ws[l][tile 0..15][j 0..31][k 0..31], tile = layer*4 + species, zeros in pads.
__global__ void convert_weights_kernel(Wptrs wp, unsigned short* __restrict__ wsb) {
  int idx = blockIdx.x * 256 + threadIdx.x;          // 65536 total
  const int NLs[4] = {24, 20, 16, 12};
  int l = idx >> 14, r = idx & 16383;
  int tile = r >> 10, j = (r >> 5) & 31, k = r & 31;
  int s = tile & 3, layer = tile >> 2;
  int NL = NLs[l];
  const float* w = wp.p[l * 4 + layer];
  float v = 0.0f;
  if (layer == 0)      { if (k < NL) v = w[(s * NL + k) * 32 + j] * -1.4426950408889634f; }
  else if (layer == 3) { if (j < NL) v = w[(s * 32 + k) * NL + j] * -0.6931471805599453f; }
  else                 { v = w[(s * 32 + k) * 32 + j]; }
  wsb[idx] = (unsigned short)bfb(v);
}

__global__ __launch_bounds__(THREADS, 8) void RadialBasis_51316269253437_kernel(
    const float* __restrict__ rad, const int* __restrict__ spc,
    const unsigned short* __restrict__ wsb, float* __restrict__ out, int npairs)
{
  // LDS: s_in 12288 + s_out 27648 + s_pos 384 + ctrl 68 -> 40448 B -> 4 blocks/CU.
  __shared__ unsigned short s_in[ROWS * 32];
  __shared__ unsigned short s_out[ROWS * 72];
  __shared__ unsigned short s_pos[ROWS];
  __shared__ int s_cnt[4], s_fill[4], s_off[4], s_gpre[5];
  const int tid = threadIdx.x;
  const int base = blockIdx.x * ROWS;
  int vb = npairs - base; if (vb > ROWS) vb = ROWS;

  if (tid < 4) { s_cnt[tid] = 0; s_fill[tid] = 0; }
  __syncthreads();
  int sp = -1;
  if (tid < vb) sp = spc[base + tid];
  if (sp >= 0) atomicAdd(&s_cnt[sp], 1);
  __syncthreads();
  if (tid == 0) {
    int o = 0, gp = 0;
    #pragma unroll
    for (int s4 = 0; s4 < 4; ++s4) {
      s_off[s4] = o; o += s_cnt[s4];
      s_gpre[s4] = gp; gp += (s_cnt[s4] + 31) >> 5;
    }
    s_gpre[4] = gp;
  }
  __syncthreads();
  if (sp >= 0) {
    int pos = s_off[sp] + atomicAdd(&s_fill[sp], 1);
    s_pos[tid] = (unsigned short)pos;
  }

  float4 L[3];
  // phase 0 staging (loads can issue while the sort completes)
  load3<24, 0>(rad, base, vb, tid, L);
  __syncthreads();                   // sort results visible
  write3(s_in, s_pos, vb, tid, L);
  __syncthreads();

  // phase 0: prefetch phase-1 slice, compute, then write it after the barrier
  load3<20, 24>(rad, base, vb, tid, L);
  computePhase<24,  0,  0>(wsb, s_in, s_out, s_cnt, s_off, s_gpre, tid);
  __syncthreads();
  write3(s_in, s_pos, vb, tid, L);
  __syncthreads();

  // phase 1
  load3<16, 44>(rad, base, vb, tid, L);
  computePhase<20, 24, 16>(wsb, s_in, s_out, s_cnt, s_off, s_gpre, tid);
  __syncthreads();
  write3(s_in, s_pos, vb, tid, L);
  __syncthreads();

  // phase 2
  load3<12, 60>(rad, base, vb, tid, L);
  computePhase<16, 44, 32>(wsb, s_in, s_out, s_cnt, s_off, s_gpre, tid);
  __syncthreads();
  write3(s_in, s_pos, vb, tid, L);
  __syncthreads();

  // phase 3 (no prefetch)
  computePhase<12, 60, 48>(wsb, s_in, s_out, s_cnt, s_off, s_gpre, tid);
  __syncthreads();

  // single stage-out: permuted LDS read (natural 72-col rows) -> coalesced float4 writes
  for (int j = tid; j < vb * 18; j += THREADS) {
    int i = j / 18, q = j - i * 18;
    uint2 w = *(const uint2*)(s_out + (int)s_pos[i] * 72 + q * 4);
    float4 v = make_float4(bf2f((unsigned short)(w.x & 0xffff)),
                           bf2f((unsigned short)(w.x >> 16)),
                           bf2f((unsigned short)(w.y & 0xffff)),
                           bf2f((unsigned short)(w.y >> 16)));
    *(float4*)(out + (long)(base + i) * 72 + q * 4) = v;
  }
}

extern "C" void kernel_launch(void* const* d_in, const int* in_sizes, int n_in,
                              void* d_out, int out_size, void* d_ws, size_t ws_size,
                              hipStream_t stream) {
  const float* rad = (const float*)d_in[0];
  const int* spc = (const int*)d_in[1];
  Wptrs wp;
  for (int i = 0; i < 16; ++i) wp.p[i] = (const float*)d_in[2 + i];
  float* out = (float*)d_out;
  unsigned short* wsb = (unsigned short*)d_ws;
  int npairs = in_sizes[0] / 72;

  convert_weights_kernel<<<dim3(256), dim3(256), 0, stream>>>(wp, wsb);
  int grid = (npairs + ROWS - 1) / ROWS;
  RadialBasis_51316269253437_kernel<<<dim3(grid), dim3(THREADS), 0, stream>>>(rad, spc, wsb, out, npairs);
}

// Round 17
// 312.423 us; speedup vs baseline: 1.1356x; 1.1356x over previous
//
#include <hip/hip_runtime.h>

typedef __attribute__((ext_vector_type(8))) short bf16x8;
typedef __attribute__((ext_vector_type(16))) float f32x16;

union FragU { bf16x8 v; unsigned int u[4]; };
struct Wptrs { const float* p[16]; };

#define ROWS 192
#define THREADS 512

__device__ __forceinline__ unsigned int bfb(float f) {
  unsigned int u = __builtin_bit_cast(unsigned int, f);
  return (u + 0x7fffu + ((u >> 16) & 1u)) >> 16;   // RNE f32 -> bf16 bits
}
__device__ __forceinline__ unsigned int cvtpk(float lo, float hi) {
  unsigned int d;
  asm("v_cvt_pk_bf16_f32 %0, %1, %2" : "=v"(d) : "v"(lo), "v"(hi));
  return d;
}
__device__ __forceinline__ float bf2f(unsigned short b) {
  return __builtin_bit_cast(float, (unsigned int)b << 16);
}
__device__ __forceinline__ f32x16 zero16() {
  f32x16 z;
  #pragma unroll
  for (int i = 0; i < 16; ++i) z[i] = 0.0f;
  return z;
}
__device__ __forceinline__ bf16x8 ldA(const unsigned short* __restrict__ wsb, int tile, int l31, int hi, int h) {
  return *(const bf16x8*)(wsb + ((tile * 32 + l31) << 5) + h * 16 + hi * 8);
}

// Weight-folded silu (W1 pre-scaled by c = -log2(e), W4 by -ln2; c*(-ln2)=1):
// acc arrives as a = c*z; next-layer input is h' = a * rcp(1 + exp2(a)).
// Pairwise shared reciprocal (R15-passed): r = rcp(d0*d1), h0 = a0*r*d1, ...
// C layout (32x32x16): col p = lane&31, row j = (reg&3)+8*(reg>>2)+4*hi.
// Next-layer B frags via 4x v_permlane32_swap_b32 (verified R1-R16 network).
__device__ __forceinline__ void transition(const f32x16& acc, bf16x8& b0, bf16x8& b1) {
  unsigned int P[8];
  #pragma unroll
  for (int t = 0; t < 8; ++t) {
    float a0 = acc[2*t], a1 = acc[2*t+1];
    float d0 = 1.0f + __builtin_amdgcn_exp2f(a0);
    float d1 = 1.0f + __builtin_amdgcn_exp2f(a1);
    float r  = __builtin_amdgcn_rcpf(d0 * d1);
    float h0 = a0 * r * d1;
    float h1 = a1 * r * d0;
    P[t] = cvtpk(h0, h1);
  }
  asm volatile("v_permlane32_swap_b32 %0, %1" : "+v"(P[0]), "+v"(P[2]));
  asm volatile("v_permlane32_swap_b32 %0, %1" : "+v"(P[1]), "+v"(P[3]));
  asm volatile("v_permlane32_swap_b32 %0, %1" : "+v"(P[4]), "+v"(P[6]));
  asm volatile("v_permlane32_swap_b32 %0, %1" : "+v"(P[5]), "+v"(P[7]));
  FragU f0, f1;
  f0.u[0] = P[0]; f0.u[1] = P[1]; f0.u[2] = P[2]; f0.u[3] = P[3];
  f1.u[0] = P[4]; f1.u[1] = P[5]; f1.u[2] = P[6]; f1.u[3] = P[7];
  b0 = f0.v; b1 = f1.v;
}

// T14 async-STAGE split. vb*8 <= 1536 = 3*THREADS -> fixed 3 quads/thread.
// load3: issue the global loads for a phase slice (pads/out-of-range = 0).
template<int NL, int OFF>
__device__ __forceinline__ void load3(const float* __restrict__ rad,
    int base, int vb, int tid, float4* L)
{
  #pragma unroll
  for (int k = 0; k < 3; ++k) {
    int j = tid + k * THREADS, i = j >> 3, q = j & 7;
    float4 g = make_float4(0.f, 0.f, 0.f, 0.f);
    if (q < NL / 4 && i < vb)
      g = *(const float4*)(rad + (long)(base + i) * 72 + OFF + q * 4);
    L[k] = g;
  }
}
// write3: pack + permuted LDS write (zeros land in the K-pads).
__device__ __forceinline__ void write3(unsigned short* __restrict__ s_in,
    const unsigned short* __restrict__ s_pos, int vb, int tid, const float4* L)
{
  #pragma unroll
  for (int k = 0; k < 3; ++k) {
    int j = tid + k * THREADS, i = j >> 3, q = j & 7;
    if (i < vb) {
      *(uint2*)(s_in + (int)s_pos[i] * 32 + q * 4) =
          make_uint2(cvtpk(L[k].x, L[k].y), cvtpk(L[k].z, L[k].w));
    }
  }
}

// Compute only (R13-verbatim body): species-uniform 32-row groups.
template<int NL, int OFF, int TB>
__device__ __forceinline__ void computePhase(const unsigned short* __restrict__ wsb,
    const unsigned short* __restrict__ s_in, unsigned short* __restrict__ s_out,
    const int* s_cnt, const int* s_off, const int* s_gpre, int tid)
{
  const int lane = tid & 63, wid = tid >> 6;
  const int l31 = lane & 31, hi = lane >> 5;
  const f32x16 Z = zero16();
  const int Gtot = s_gpre[4];
  for (int g = wid; g < Gtot; g += THREADS / 64) {
    int s = (g >= s_gpre[1]) + (g >= s_gpre[2]) + (g >= s_gpre[3]);
    int gi = g - s_gpre[s];
    int goff = s_off[s] + gi * 32;
    int gcnt = s_cnt[s] - gi * 32; if (gcnt > 32) gcnt = 32;
    int li = l31 < gcnt ? l31 : gcnt - 1;
    int row = goff + li;

    FragU bx0, bx1;
    bx0.v = *(const bf16x8*)(s_in + row * 32 + hi * 8);
    if (NL > 16) bx1.v = *(const bf16x8*)(s_in + row * 32 + 16 + hi * 8);

    f32x16 acc;
    acc = __builtin_amdgcn_mfma_f32_32x32x16_bf16(ldA(wsb, TB + s, l31, hi, 0), bx0.v, Z, 0, 0, 0);
    if (NL > 16)
      acc = __builtin_amdgcn_mfma_f32_32x32x16_bf16(ldA(wsb, TB + s, l31, hi, 1), bx1.v, acc, 0, 0, 0);
    bf16x8 b0, b1;
    transition(acc, b0, b1);
    acc = __builtin_amdgcn_mfma_f32_32x32x16_bf16(ldA(wsb, TB + 4 + s, l31, hi, 0), b0, Z, 0, 0, 0);
    acc = __builtin_amdgcn_mfma_f32_32x32x16_bf16(ldA(wsb, TB + 4 + s, l31, hi, 1), b1, acc, 0, 0, 0);
    transition(acc, b0, b1);
    acc = __builtin_amdgcn_mfma_f32_32x32x16_bf16(ldA(wsb, TB + 8 + s, l31, hi, 0), b0, Z, 0, 0, 0);
    acc = __builtin_amdgcn_mfma_f32_32x32x16_bf16(ldA(wsb, TB + 8 + s, l31, hi, 1), b1, acc, 0, 0, 0);
    transition(acc, b0, b1);
    acc = __builtin_amdgcn_mfma_f32_32x32x16_bf16(ldA(wsb, TB + 12 + s, l31, hi, 0), b0, Z, 0, 0, 0);
    acc = __builtin_amdgcn_mfma_f32_32x32x16_bf16(ldA(wsb, TB + 12 + s, l31, hi, 1), b1, acc, 0, 0, 0);

    // store: reg quad t -> jo = 8t + 4hi + 0..3 ; natural 72-stride s_out
    if (l31 < gcnt) {
      int obase = (goff + l31) * 72 + OFF;
      #pragma unroll
      for (int t = 0; t < 4; ++t) {
        if (8 * t + 4 * hi + 4 <= NL) {
          *(uint2*)(s_out + obase + 8 * t + 4 * hi) =
              make_uint2(cvtpk(acc[4*t], acc[4*t+1]), cvtpk(acc[4*t+2], acc[4*t+3]));
        }
      }
    }
  }
}

// weights -> bf16 fragment-ready layout in d_ws, with silu-constant folding:
// layer 0 (W1) scaled by -log2(e); layer 3 (W4) scaled by -ln2; W2/W3 as-is.
// ws[l][tile 0..15][j 0..31][k 0..31], tile = layer*4 + species, zeros in pads.
__global__ void convert_weights_kernel(Wptrs wp, unsigned short* __restrict__ wsb) {
  int idx = blockIdx.x * 256 + threadIdx.x;          // 65536 total
  const int NLs[4] = {24, 20, 16, 12};
  int l = idx >> 14, r = idx & 16383;
  int tile = r >> 10, j = (r >> 5) & 31, k = r & 31;
  int s = tile & 3, layer = tile >> 2;
  int NL = NLs[l];
  const float* w = wp.p[l * 4 + layer];
  float v = 0.0f;
  if (layer == 0)      { if (k < NL) v = w[(s * NL + k) * 32 + j] * -1.4426950408889634f; }
  else if (layer == 3) { if (j < NL) v = w[(s * 32 + k) * NL + j] * -0.6931471805599453f; }
  else                 { v = w[(s * 32 + k) * 32 + j]; }
  wsb[idx] = (unsigned short)bfb(v);
}

// launch_bounds (512, 6): VGPR cap ~85 so the 12 prefetch VGPRs stay resident
// (R16's (512,8) cap made the allocator SPILL them -> +335MB scratch traffic).
// Actual occupancy remains LDS-capped: 40448 B -> 4 blocks/CU = 8 waves/SIMD,
// which needs VGPR <= 64; expected use ~48-56.
__global__ __launch_bounds__(THREADS, 6) void RadialBasis_51316269253437_kernel(
    const float* __restrict__ rad, const int* __restrict__ spc,
    const unsigned short* __restrict__ wsb, float* __restrict__ out, int npairs)
{
  // LDS: s_in 12288 + s_out 27648 + s_pos 384 + ctrl 68 -> 40448 B -> 4 blocks/CU.
  __shared__ unsigned short s_in[ROWS * 32];
  __shared__ unsigned short s_out[ROWS * 72];
  __shared__ unsigned short s_pos[ROWS];
  __shared__ int s_cnt[4], s_fill[4], s_off[4], s_gpre[5];
  const int tid = threadIdx.x;
  const int base = blockIdx.x * ROWS;
  int vb = npairs - base; if (vb > ROWS) vb = ROWS;

  if (tid < 4) { s_cnt[tid] = 0; s_fill[tid] = 0; }
  __syncthreads();
  int sp = -1;
  if (tid < vb) sp = spc[base + tid];
  if (sp >= 0) atomicAdd(&s_cnt[sp], 1);
  __syncthreads();
  if (tid == 0) {
    int o = 0, gp = 0;
    #pragma unroll
    for (int s4 = 0; s4 < 4; ++s4) {
      s_off[s4] = o; o += s_cnt[s4];
      s_gpre[s4] = gp; gp += (s_cnt[s4] + 31) >> 5;
    }
    s_gpre[4] = gp;
  }
  __syncthreads();
  if (sp >= 0) {
    int pos = s_off[sp] + atomicAdd(&s_fill[sp], 1);
    s_pos[tid] = (unsigned short)pos;
  }

  float4 L[3];
  // phase 0 staging (loads can issue while the sort completes)
  load3<24, 0>(rad, base, vb, tid, L);
  __syncthreads();                   // sort results visible
  write3(s_in, s_pos, vb, tid, L);
  __syncthreads();

  // phase 0: prefetch phase-1 slice, compute, then write it after the barrier
  load3<20, 24>(rad, base, vb, tid, L);
  computePhase<24,  0,  0>(wsb, s_in, s_out, s_cnt, s_off, s_gpre, tid);
  __syncthreads();
  write3(s_in, s_pos, vb, tid, L);
  __syncthreads();

  // phase 1
  load3<16, 44>(rad, base, vb, tid, L);
  computePhase<20, 24, 16>(wsb, s_in, s_out, s_cnt, s_off, s_gpre, tid);
  __syncthreads();
  write3(s_in, s_pos, vb, tid, L);
  __syncthreads();

  // phase 2
  load3<12, 60>(rad, base, vb, tid, L);
  computePhase<16, 44, 32>(wsb, s_in, s_out, s_cnt, s_off, s_gpre, tid);
  __syncthreads();
  write3(s_in, s_pos, vb, tid, L);
  __syncthreads();

  // phase 3 (no prefetch)
  computePhase<12, 60, 48>(wsb, s_in, s_out, s_cnt, s_off, s_gpre, tid);
  __syncthreads();

  // single stage-out: permuted LDS read (natural 72-col rows) -> coalesced float4 writes
  for (int j = tid; j < vb * 18; j += THREADS) {
    int i = j / 18, q = j - i * 18;
    uint2 w = *(const uint2*)(s_out + (int)s_pos[i] * 72 + q * 4);
    float4 v = make_float4(bf2f((unsigned short)(w.x & 0xffff)),
                           bf2f((unsigned short)(w.x >> 16)),
                           bf2f((unsigned short)(w.y & 0xffff)),
                           bf2f((unsigned short)(w.y >> 16)));
    *(float4*)(out + (long)(base + i) * 72 + q * 4) = v;
  }
}

extern "C" void kernel_launch(void* const* d_in, const int* in_sizes, int n_in,
                              void* d_out, int out_size, void* d_ws, size_t ws_size,
                              hipStream_t stream) {
  const float* rad = (const float*)d_in[0];
  const int* spc = (const int*)d_in[1];
  Wptrs wp;
  for (int i = 0; i < 16; ++i) wp.p[i] = (const float*)d_in[2 + i];
  float* out = (float*)d_out;
  unsigned short* wsb = (unsigned short*)d_ws;
  int npairs = in_sizes[0] / 72;

  convert_weights_kernel<<<dim3(256), dim3(256), 0, stream>>>(wp, wsb);
  int grid = (npairs + ROWS - 1) / ROWS;
  RadialBasis_51316269253437_kernel<<<dim3(grid), dim3(THREADS), 0, stream>>>(rad, spc, wsb, out, npairs);
}